// Round 5
// baseline (409.948 us; speedup 1.0000x reference)
//
#include <hip/hip_runtime.h>
#include <math.h>

#define NF 8
#define NQ 300
#define HSZ 96
#define WSZ 96
#define HW 9216
#define DTOT 73728
#define NT 256
#define NTP 192
#define NBF 16

// ws float offsets
#define WS_TGTY 0        // [16][96] max over h
#define WS_TGTX 1536     // [16][96] max over w
#define WS_TSUM 3072     // [16]
#define WS_YSUM 3088     // [16]
#define WS_XSUM 3104     // [16]
#define WS_TBITS 3200    // 16 planes * 288 u32 (tmask bits)
#define WS_PBITS 7808    // 2 planes * 288 u32 (vpad bits)
#define WS_PART  8448    // [4800][8] partials

__device__ __forceinline__ float sigmoid_fast(float x) {
    float e = __expf(-fabsf(x));
    float inv = __builtin_amdgcn_rcpf(1.f + e);
    return x >= 0.f ? inv : e * inv;
}

// one block per (b,f): target projections/sums + bit-pack tmask (and vpad for 2 blocks)
__global__ __launch_bounds__(NT)
void targets_kernel(const float* __restrict__ tm, const unsigned char* __restrict__ vpad,
                    float* __restrict__ ws) {
    int bf = blockIdx.x, t = threadIdx.x;
    int lane = t & 63, wv = t >> 6;
    __shared__ float tile[HSZ * 97];
    __shared__ float red[4][4];
    unsigned long long* tb64 = (unsigned long long*)(ws + WS_TBITS) + bf * 144;
    const float* base = tm + (size_t)bf * HW;
    float tsum = 0.f;
    #pragma unroll
    for (int it = 0; it < 36; ++it) {
        int e = it * NT + t;
        float v = base[e];
        tsum += v;
        unsigned long long bt = __ballot(v != 0.f);
        if (lane == 0) tb64[it * 4 + wv] = bt;
        tile[e + e / 96] = v;        // stride-97 padded
    }
    if ((bf & 7) == 0) {             // pack vpad plane b (block-uniform branch)
        int b = bf >> 3;
        unsigned long long* pb64 = (unsigned long long*)(ws + WS_PBITS) + b * 144;
        const unsigned char* pp = vpad + (size_t)b * HW;
        #pragma unroll
        for (int it = 0; it < 36; ++it) {
            int e = it * NT + t;
            unsigned long long bt = __ballot(pp[e] != 0);
            if (lane == 0) pb64[it * 4 + wv] = bt;
        }
    }
    __syncthreads();
    float ysum = 0.f, xsum = 0.f;
    if (t < 96) {
        float m = -INFINITY;
        #pragma unroll 8
        for (int h = 0; h < HSZ; ++h) m = fmaxf(m, tile[h * 97 + t]);
        ws[WS_TGTY + bf * 96 + t] = m;
        ysum = m;
    } else if (t < 192) {
        int hh = t - 96;
        float m = -INFINITY;
        #pragma unroll 8
        for (int w = 0; w < WSZ; ++w) m = fmaxf(m, tile[hh * 97 + w]);
        ws[WS_TGTX + bf * 96 + hh] = m;
        xsum = m;
    }
    float v0 = tsum, v1 = ysum, v2 = xsum;
    #pragma unroll
    for (int off = 32; off > 0; off >>= 1) {
        v0 += __shfl_down(v0, off, 64);
        v1 += __shfl_down(v1, off, 64);
        v2 += __shfl_down(v2, off, 64);
    }
    if (lane == 0) { red[wv][0] = v0; red[wv][1] = v1; red[wv][2] = v2; }
    __syncthreads();
    if (t == 0) {
        #pragma unroll
        for (int w = 1; w < 4; ++w) { v0 += red[w][0]; v1 += red[w][1]; v2 += red[w][2]; }
        ws[WS_TSUM + bf] = v0;
        ws[WS_YSUM + bf] = v1;
        ws[WS_XSUM + bf] = v2;
    }
}

// one block per (b,f,q), 192 threads. Column-strip mapping: thread t owns
// cols 4*w4..4*w4+3 (w4=t%24) and rows g+8k (g=t/24, k=0..11). float4 index
// = t + 192k (perfectly coalesced). Col/row maxes in registers -> tiny LDS.
__global__ __launch_bounds__(NTP, 8)
void partial_kernel(const float* __restrict__ masks, const float* __restrict__ ws,
                    float* __restrict__ part) {
    int blk = blockIdx.x;
    int bf = blk / NQ;
    int q  = blk - bf * NQ;
    int b  = bf >> 3;
    int t  = threadIdx.x;
    int w4 = t % 24;
    int g  = t / 24;

    __shared__ float rowp[HSZ * 25];     // row-max partials, 25-padded
    __shared__ float colp[8 * HSZ];      // col-max partials per g
    __shared__ float red[3][8];

    const float4* mrow = (const float4*)(masks + (size_t)(bf * NQ + q) * HW);
    const unsigned* tb = (const unsigned*)(ws + WS_TBITS) + bf * 288;
    const unsigned* pb = (const unsigned*)(ws + WS_PBITS) + b * 288;

    int widx = t >> 3;               // dword sub-index (0..23)
    int sh = (t & 7) * 4;            // nibble shift

    // 1-deep rolling prefetch
    float4 cur = mrow[t];
    unsigned twc = tb[widx] >> sh;
    unsigned pwc = pb[widx] >> sh;

    float focal = 0.f, dnum = 0.f, dden = 0.f;
    float cm0 = -INFINITY, cm1 = -INFINITY, cm2 = -INFINITY, cm3 = -INFINITY;

    #pragma unroll
    for (int k = 0; k < 12; ++k) {
        float4 nxt = cur;
        unsigned twn = 0u, pwn = 0u;
        if (k < 11) {
            nxt = mrow[(k + 1) * NTP + t];
            twn = tb[(k + 1) * 24 + widx] >> sh;
            pwn = pb[(k + 1) * 24 + widx] >> sh;
        }
        float xs[4] = {cur.x, cur.y, cur.z, cur.w};
        if (pwc & 0xFu) {                         // execz-skipped when no padding
            #pragma unroll
            for (int j = 0; j < 4; ++j)
                if ((pwc >> j) & 1u) xs[j] = 0.f;
        }
        #pragma unroll
        for (int j = 0; j < 4; ++j) {
            float x = xs[j];
            float tg = (float)((twc >> j) & 1u);
            float ee = __expf(-fabsf(x));
            float se = 1.f + ee;
            float inv = __builtin_amdgcn_rcpf(se);
            float s = x >= 0.f ? inv : ee * inv;          // sigmoid(x)
            float L = __logf(se);                          // log1p(exp(-|x|))
            float ce = fmaxf(x, 0.f) - x * tg + L;
            float omp = s + tg - 2.f * s * tg;             // 1 - p_t
            float at = 0.75f - 0.5f * tg;                  // alpha_t
            focal = fmaf(at * ce, omp * omp, focal);
            dnum = fmaf(s, tg, dnum);
            dden += s;
        }
        cm0 = fmaxf(cm0, xs[0]); cm1 = fmaxf(cm1, xs[1]);
        cm2 = fmaxf(cm2, xs[2]); cm3 = fmaxf(cm3, xs[3]);
        float rm = fmaxf(fmaxf(xs[0], xs[1]), fmaxf(xs[2], xs[3]));
        rowp[(g + 8 * k) * 25 + w4] = rm;
        cur = nxt; twc = twn; pwc = pwn;
    }
    ((float4*)colp)[g * 24 + w4] = make_float4(cm0, cm1, cm2, cm3);
    __syncthreads();

    float pYn = 0.f, pYd = 0.f, pXn = 0.f, pXd = 0.f;
    if (t < 96) {
        float m = colp[t];
        #pragma unroll
        for (int gg = 1; gg < 8; ++gg) m = fmaxf(m, colp[gg * 96 + t]);
        float sg = sigmoid_fast(m);
        pYd = sg;
        pYn = sg * ws[WS_TGTY + bf * 96 + t];
    } else {
        int r = t - 96;
        float m = rowp[r * 25];
        #pragma unroll
        for (int w = 1; w < 24; ++w) m = fmaxf(m, rowp[r * 25 + w]);
        float sg = sigmoid_fast(m);
        pXd = sg;
        pXn = sg * ws[WS_TGTX + bf * 96 + r];
    }

    // single-barrier 7-way block reduction over 3 waves
    float v[7] = {focal, dnum, dden, pYn, pYd, pXn, pXd};
    #pragma unroll
    for (int k = 0; k < 7; ++k)
        #pragma unroll
        for (int off = 32; off > 0; off >>= 1) v[k] += __shfl_down(v[k], off, 64);
    int wv = t >> 6, lane = t & 63;
    if (lane == 0) {
        #pragma unroll
        for (int k = 0; k < 7; ++k) red[wv][k] = v[k];
    }
    __syncthreads();
    if (t == 0) {
        #pragma unroll
        for (int w = 1; w < 3; ++w)
            #pragma unroll
            for (int k = 0; k < 7; ++k) v[k] += red[w][k];
        float4* p = (float4*)(part + (size_t)blk * 8);
        p[0] = make_float4(v[0], v[1], v[2], v[3]);
        p[1] = make_float4(v[4], v[5], v[6], 0.f);
    }
}

// grid=2 (one block per b): combine partials + class/bbox/giou, then argmin
__global__ __launch_bounds__(NT)
void final_kernel(const float* __restrict__ logits, const float* __restrict__ boxes,
                  const float* __restrict__ tbox, const int* __restrict__ tvalid,
                  const float* __restrict__ ws, float* __restrict__ out, int write_idx) {
    int b = blockIdx.x, t = threadIdx.x;
    const float* part = ws + WS_PART;

    float best = INFINITY;
    int bi = 0x7fffffff;

    for (int q = t; q < NQ; q += NT) {
        float focal = 0.f, dnum = 0.f, dden = 0.f;
        float pYn = 0.f, pYd = 0.f, pXn = 0.f, pXd = 0.f;
        float tsum = 0.f, ysum = 0.f, xsum = 0.f;
        #pragma unroll
        for (int f = 0; f < NF; ++f) {
            int bf = b * NF + f;
            const float4* p = (const float4*)(part + (size_t)(bf * NQ + q) * 8);
            float4 pa = p[0], pbv = p[1];
            focal += pa.x; dnum += pa.y; dden += pa.z; pYn += pa.w;
            pYd += pbv.x; pXn += pbv.y; pXd += pbv.z;
            tsum += ws[WS_TSUM + bf];
            ysum += ws[WS_YSUM + bf];
            xsum += ws[WS_XSUM + bf];
        }
        float cost_mask = focal / (float)DTOT;
        float cost_dice = -(2.f * dnum + 1.f) / (dden + tsum + 1.f);
        float coefY = (2.f * pYn + 1.f) / (pYd + ysum + 1.f);
        float coefX = (2.f * pXn + 1.f) / (pXd + xsum + 1.f);
        float cost_proj = -0.5f * (coefY + coefX);

        float wsum = 0.f, cls = 0.f, cb = 0.f, cg = 0.f;
        #pragma unroll
        for (int f = 0; f < NF; ++f) {
            float wv = (tvalid[b * NF + f] != 0) ? 1.f : 0.f;
            wsum += wv;
            float lg = logits[(b * NF + f) * NQ + q];
            float p = sigmoid_fast(lg);
            float negc = 0.75f * p * p * (-__logf(1.f - p + 1e-8f));
            float posc = 0.25f * (1.f - p) * (1.f - p) * (-__logf(p + 1e-8f));
            cls += (posc - negc) * wv;

            const float* bx = boxes + (size_t)((b * NF + f) * NQ + q) * 4;
            const float* tbp = tbox + (b * NF + f) * 4;
            float cx = bx[0], cy = bx[1], bw = bx[2], bh = bx[3];
            float tcx = tbp[0], tcy = tbp[1], tbw = tbp[2], tbh = tbp[3];
            cb += fabsf(cx - tcx) + fabsf(cy - tcy) + fabsf(bw - tbw) + fabsf(bh - tbh);
            float sx1 = cx - 0.5f * bw, sy1 = cy - 0.5f * bh;
            float sx2 = cx + 0.5f * bw, sy2 = cy + 0.5f * bh;
            float tx1 = tcx - 0.5f * tbw, ty1 = tcy - 0.5f * tbh;
            float tx2 = tcx + 0.5f * tbw, ty2 = tcy + 0.5f * tbh;
            float a1 = (sx2 - sx1) * (sy2 - sy1), a2 = (tx2 - tx1) * (ty2 - ty1);
            float iw = fmaxf(fminf(sx2, tx2) - fmaxf(sx1, tx1), 0.f);
            float ih = fmaxf(fminf(sy2, ty2) - fmaxf(sy1, ty1), 0.f);
            float inter = iw * ih;
            float uni = a1 + a2 - inter;
            float iou = inter / uni;
            float cw = fmaxf(fmaxf(sx2, tx2) - fminf(sx1, tx1), 0.f);
            float chh = fmaxf(fmaxf(sy2, ty2) - fminf(sy1, ty1), 0.f);
            float areac = cw * chh;
            cg += -(iou - (areac - uni) / areac);
        }
        cls /= wsum;
        float c = cls + 0.125f * cb + 0.125f * cg + cost_mask + cost_dice + cost_proj;
        out[b * NQ + q] = c;
        if (c < best) { best = c; bi = q; }
    }

    #pragma unroll
    for (int off = 32; off > 0; off >>= 1) {
        float ov = __shfl_down(best, off, 64);
        int oi = __shfl_down(bi, off, 64);
        if (ov < best || (ov == best && oi < bi)) { best = ov; bi = oi; }
    }
    __shared__ float rv[4];
    __shared__ int ri[4];
    int wv = t >> 6, lane = t & 63;
    if (lane == 0) { rv[wv] = best; ri[wv] = bi; }
    __syncthreads();
    if (t == 0 && write_idx) {
        #pragma unroll
        for (int w = 1; w < 4; ++w) {
            if (rv[w] < best || (rv[w] == best && ri[w] < bi)) { best = rv[w]; bi = ri[w]; }
        }
        out[2 * NQ + b] = (float)bi;       // src_ind
        out[2 * NQ + 2 + b] = 0.f;         // tgt_ind
    }
}

extern "C" void kernel_launch(void* const* d_in, const int* in_sizes, int n_in,
                              void* d_out, int out_size, void* d_ws, size_t ws_size,
                              hipStream_t stream) {
    const float* logits = (const float*)d_in[0];
    const float* boxes  = (const float*)d_in[1];
    const float* masks  = (const float*)d_in[2];
    const float* tmask  = (const float*)d_in[3];
    const float* tbox   = (const float*)d_in[4];
    const int*   tvalid = (const int*)d_in[5];
    const unsigned char* vpad = (const unsigned char*)d_in[6];
    float* out = (float*)d_out;
    float* ws  = (float*)d_ws;

    targets_kernel<<<NBF, NT, 0, stream>>>(tmask, vpad, ws);
    partial_kernel<<<NBF * NQ, NTP, 0, stream>>>(masks, ws, ws + WS_PART);
    int write_idx = (out_size >= 2 * NQ + 4) ? 1 : 0;
    final_kernel<<<2, NT, 0, stream>>>(logits, boxes, tbox, tvalid, ws, out, write_idx);
}

// Round 6
// 322.282 us; speedup vs baseline: 1.2720x; 1.2720x over previous
//
#include <hip/hip_runtime.h>
#include <math.h>

#define NF 8
#define NQ 300
#define HSZ 96
#define WSZ 96
#define HW 9216
#define DTOT 73728
#define NT 256
#define NTP 192
#define NBF 16

// ws float offsets
#define WS_TGTY 0        // [16][96] max over h
#define WS_TGTX 1536     // [16][96] max over w
#define WS_TSUM 3072     // [16]
#define WS_YSUM 3088     // [16]
#define WS_XSUM 3104     // [16]
#define WS_TBITS 3200    // 16 planes * 288 u32 (tmask bits)
#define WS_PBITS 7808    // 2 planes * 288 u32 (vpad bits)
#define WS_PART  8448    // [4800][8] partials

__device__ __forceinline__ float sigmoid_fast(float x) {
    float e = __expf(-fabsf(x));
    float inv = __builtin_amdgcn_rcpf(1.f + e);
    return x >= 0.f ? inv : e * inv;
}

// one block per (b,f): target projections/sums + bit-pack tmask (and vpad for 2 blocks)
__global__ __launch_bounds__(NT)
void targets_kernel(const float* __restrict__ tm, const unsigned char* __restrict__ vpad,
                    float* __restrict__ ws) {
    int bf = blockIdx.x, t = threadIdx.x;
    int lane = t & 63, wv = t >> 6;
    __shared__ float tile[HSZ * 97];
    __shared__ float red[4][4];
    unsigned long long* tb64 = (unsigned long long*)(ws + WS_TBITS) + bf * 144;
    const float* base = tm + (size_t)bf * HW;
    float tsum = 0.f;
    #pragma unroll
    for (int it = 0; it < 36; ++it) {
        int e = it * NT + t;
        float v = base[e];
        tsum += v;
        unsigned long long bt = __ballot(v != 0.f);
        if (lane == 0) tb64[it * 4 + wv] = bt;
        tile[e + e / 96] = v;        // stride-97 padded
    }
    if ((bf & 7) == 0) {             // pack vpad plane b (block-uniform branch)
        int b = bf >> 3;
        unsigned long long* pb64 = (unsigned long long*)(ws + WS_PBITS) + b * 144;
        const unsigned char* pp = vpad + (size_t)b * HW;
        #pragma unroll
        for (int it = 0; it < 36; ++it) {
            int e = it * NT + t;
            unsigned long long bt = __ballot(pp[e] != 0);
            if (lane == 0) pb64[it * 4 + wv] = bt;
        }
    }
    __syncthreads();
    float ysum = 0.f, xsum = 0.f;
    if (t < 96) {
        float m = -INFINITY;
        #pragma unroll 8
        for (int h = 0; h < HSZ; ++h) m = fmaxf(m, tile[h * 97 + t]);
        ws[WS_TGTY + bf * 96 + t] = m;
        ysum = m;
    } else if (t < 192) {
        int hh = t - 96;
        float m = -INFINITY;
        #pragma unroll 8
        for (int w = 0; w < WSZ; ++w) m = fmaxf(m, tile[hh * 97 + w]);
        ws[WS_TGTX + bf * 96 + hh] = m;
        xsum = m;
    }
    float v0 = tsum, v1 = ysum, v2 = xsum;
    #pragma unroll
    for (int off = 32; off > 0; off >>= 1) {
        v0 += __shfl_down(v0, off, 64);
        v1 += __shfl_down(v1, off, 64);
        v2 += __shfl_down(v2, off, 64);
    }
    if (lane == 0) { red[wv][0] = v0; red[wv][1] = v1; red[wv][2] = v2; }
    __syncthreads();
    if (t == 0) {
        #pragma unroll
        for (int w = 1; w < 4; ++w) { v0 += red[w][0]; v1 += red[w][1]; v2 += red[w][2]; }
        ws[WS_TSUM + bf] = v0;
        ws[WS_YSUM + bf] = v1;
        ws[WS_XSUM + bf] = v2;
    }
}

// one block per (b,f,q), 192 threads. Column-strip mapping: thread t owns
// cols 4*w4..4*w4+3 (w4=t%24) and rows g+8k (g=t/24, k=0..11). float4 index
// = t + 192k (perfectly coalesced). No explicit prefetch (R3/R5 spilled);
// unroll capped at 3; launch_bounds(192,6) gives the allocator ~85 VGPRs.
__global__ __launch_bounds__(NTP, 6)
void partial_kernel(const float* __restrict__ masks, const float* __restrict__ ws,
                    float* __restrict__ part) {
    int blk = blockIdx.x;
    int bf = blk / NQ;
    int q  = blk - bf * NQ;
    int b  = bf >> 3;
    int t  = threadIdx.x;
    int w4 = t % 24;
    int g  = t / 24;

    __shared__ float rowp[HSZ * 25];     // row-max partials, 25-padded
    __shared__ float colp[8 * HSZ];      // col-max partials per g
    __shared__ float red[3][8];

    const float4* mrow = (const float4*)(masks + (size_t)(bf * NQ + q) * HW);
    const unsigned* tb = (const unsigned*)(ws + WS_TBITS) + bf * 288;
    const unsigned* pb = (const unsigned*)(ws + WS_PBITS) + b * 288;

    int widx = t >> 3;               // dword sub-index (0..23)
    int sh = (t & 7) * 4;            // nibble shift

    float focal = 0.f, dnum = 0.f, dden = 0.f;
    float cm0 = -INFINITY, cm1 = -INFINITY, cm2 = -INFINITY, cm3 = -INFINITY;

    #pragma unroll 3
    for (int k = 0; k < 12; ++k) {
        float4 cur = mrow[k * NTP + t];
        unsigned twc = tb[k * 24 + widx] >> sh;
        unsigned pwc = pb[k * 24 + widx] >> sh;

        float xs[4] = {cur.x, cur.y, cur.z, cur.w};
        if (pwc & 0xFu) {                         // execz-skipped when no padding
            #pragma unroll
            for (int j = 0; j < 4; ++j)
                if ((pwc >> j) & 1u) xs[j] = 0.f;
        }
        #pragma unroll
        for (int j = 0; j < 4; ++j) {
            float x = xs[j];
            bool bit = (twc >> j) & 1u;
            float ee = __expf(-fabsf(x));
            float se = 1.f + ee;
            float inv = __builtin_amdgcn_rcpf(se);
            bool pos = x >= 0.f;
            float s   = pos ? inv : ee * inv;      // sigmoid(x)
            float oms = pos ? ee * inv : inv;      // sigmoid(-x) = 1-s
            float L = __logf(se);                   // log1p(exp(-|x|))
            float rp = fmaxf(x, 0.f);
            float ce = (bit ? rp - x : rp) + L;     // softplus of the right sign
            float omp = bit ? oms : s;              // 1 - p_t
            float at = bit ? 0.25f : 0.75f;         // alpha_t
            focal = fmaf(at * ce, omp * omp, focal);
            dnum += bit ? s : 0.f;
            dden += s;
        }
        cm0 = fmaxf(cm0, xs[0]); cm1 = fmaxf(cm1, xs[1]);
        cm2 = fmaxf(cm2, xs[2]); cm3 = fmaxf(cm3, xs[3]);
        float rm = fmaxf(fmaxf(xs[0], xs[1]), fmaxf(xs[2], xs[3]));
        rowp[(g + 8 * k) * 25 + w4] = rm;
    }
    ((float4*)colp)[g * 24 + w4] = make_float4(cm0, cm1, cm2, cm3);
    __syncthreads();

    float pYn = 0.f, pYd = 0.f, pXn = 0.f, pXd = 0.f;
    if (t < 96) {
        float m = colp[t];
        #pragma unroll
        for (int gg = 1; gg < 8; ++gg) m = fmaxf(m, colp[gg * 96 + t]);
        float sg = sigmoid_fast(m);
        pYd = sg;
        pYn = sg * ws[WS_TGTY + bf * 96 + t];
    } else {
        int r = t - 96;
        float m = rowp[r * 25];
        #pragma unroll
        for (int w = 1; w < 24; ++w) m = fmaxf(m, rowp[r * 25 + w]);
        float sg = sigmoid_fast(m);
        pXd = sg;
        pXn = sg * ws[WS_TGTX + bf * 96 + r];
    }

    // single-barrier 7-way block reduction over 3 waves
    float v[7] = {focal, dnum, dden, pYn, pYd, pXn, pXd};
    #pragma unroll
    for (int k = 0; k < 7; ++k)
        #pragma unroll
        for (int off = 32; off > 0; off >>= 1) v[k] += __shfl_down(v[k], off, 64);
    int wv = t >> 6, lane = t & 63;
    if (lane == 0) {
        #pragma unroll
        for (int k = 0; k < 7; ++k) red[wv][k] = v[k];
    }
    __syncthreads();
    if (t == 0) {
        #pragma unroll
        for (int w = 1; w < 3; ++w)
            #pragma unroll
            for (int k = 0; k < 7; ++k) v[k] += red[w][k];
        float4* p = (float4*)(part + (size_t)blk * 8);
        p[0] = make_float4(v[0], v[1], v[2], v[3]);
        p[1] = make_float4(v[4], v[5], v[6], 0.f);
    }
}

// grid=2 (one block per b): combine partials + class/bbox/giou, then argmin
__global__ __launch_bounds__(NT)
void final_kernel(const float* __restrict__ logits, const float* __restrict__ boxes,
                  const float* __restrict__ tbox, const int* __restrict__ tvalid,
                  const float* __restrict__ ws, float* __restrict__ out, int write_idx) {
    int b = blockIdx.x, t = threadIdx.x;
    const float* part = ws + WS_PART;

    float best = INFINITY;
    int bi = 0x7fffffff;

    for (int q = t; q < NQ; q += NT) {
        float focal = 0.f, dnum = 0.f, dden = 0.f;
        float pYn = 0.f, pYd = 0.f, pXn = 0.f, pXd = 0.f;
        float tsum = 0.f, ysum = 0.f, xsum = 0.f;
        #pragma unroll
        for (int f = 0; f < NF; ++f) {
            int bf = b * NF + f;
            const float4* p = (const float4*)(part + (size_t)(bf * NQ + q) * 8);
            float4 pa = p[0], pbv = p[1];
            focal += pa.x; dnum += pa.y; dden += pa.z; pYn += pa.w;
            pYd += pbv.x; pXn += pbv.y; pXd += pbv.z;
            tsum += ws[WS_TSUM + bf];
            ysum += ws[WS_YSUM + bf];
            xsum += ws[WS_XSUM + bf];
        }
        float cost_mask = focal / (float)DTOT;
        float cost_dice = -(2.f * dnum + 1.f) / (dden + tsum + 1.f);
        float coefY = (2.f * pYn + 1.f) / (pYd + ysum + 1.f);
        float coefX = (2.f * pXn + 1.f) / (pXd + xsum + 1.f);
        float cost_proj = -0.5f * (coefY + coefX);

        float wsum = 0.f, cls = 0.f, cb = 0.f, cg = 0.f;
        #pragma unroll
        for (int f = 0; f < NF; ++f) {
            float wv = (tvalid[b * NF + f] != 0) ? 1.f : 0.f;
            wsum += wv;
            float lg = logits[(b * NF + f) * NQ + q];
            float p = sigmoid_fast(lg);
            float negc = 0.75f * p * p * (-__logf(1.f - p + 1e-8f));
            float posc = 0.25f * (1.f - p) * (1.f - p) * (-__logf(p + 1e-8f));
            cls += (posc - negc) * wv;

            const float* bx = boxes + (size_t)((b * NF + f) * NQ + q) * 4;
            const float* tbp = tbox + (b * NF + f) * 4;
            float cx = bx[0], cy = bx[1], bw = bx[2], bh = bx[3];
            float tcx = tbp[0], tcy = tbp[1], tbw = tbp[2], tbh = tbp[3];
            cb += fabsf(cx - tcx) + fabsf(cy - tcy) + fabsf(bw - tbw) + fabsf(bh - tbh);
            float sx1 = cx - 0.5f * bw, sy1 = cy - 0.5f * bh;
            float sx2 = cx + 0.5f * bw, sy2 = cy + 0.5f * bh;
            float tx1 = tcx - 0.5f * tbw, ty1 = tcy - 0.5f * tbh;
            float tx2 = tcx + 0.5f * tbw, ty2 = tcy + 0.5f * tbh;
            float a1 = (sx2 - sx1) * (sy2 - sy1), a2 = (tx2 - tx1) * (ty2 - ty1);
            float iw = fmaxf(fminf(sx2, tx2) - fmaxf(sx1, tx1), 0.f);
            float ih = fmaxf(fminf(sy2, ty2) - fmaxf(sy1, ty1), 0.f);
            float inter = iw * ih;
            float uni = a1 + a2 - inter;
            float iou = inter / uni;
            float cw = fmaxf(fmaxf(sx2, tx2) - fminf(sx1, tx1), 0.f);
            float chh = fmaxf(fmaxf(sy2, ty2) - fminf(sy1, ty1), 0.f);
            float areac = cw * chh;
            cg += -(iou - (areac - uni) / areac);
        }
        cls /= wsum;
        float c = cls + 0.125f * cb + 0.125f * cg + cost_mask + cost_dice + cost_proj;
        out[b * NQ + q] = c;
        if (c < best) { best = c; bi = q; }
    }

    #pragma unroll
    for (int off = 32; off > 0; off >>= 1) {
        float ov = __shfl_down(best, off, 64);
        int oi = __shfl_down(bi, off, 64);
        if (ov < best || (ov == best && oi < bi)) { best = ov; bi = oi; }
    }
    __shared__ float rv[4];
    __shared__ int ri[4];
    int wv = t >> 6, lane = t & 63;
    if (lane == 0) { rv[wv] = best; ri[wv] = bi; }
    __syncthreads();
    if (t == 0 && write_idx) {
        #pragma unroll
        for (int w = 1; w < 4; ++w) {
            if (rv[w] < best || (rv[w] == best && ri[w] < bi)) { best = rv[w]; bi = ri[w]; }
        }
        out[2 * NQ + b] = (float)bi;       // src_ind
        out[2 * NQ + 2 + b] = 0.f;         // tgt_ind
    }
}

extern "C" void kernel_launch(void* const* d_in, const int* in_sizes, int n_in,
                              void* d_out, int out_size, void* d_ws, size_t ws_size,
                              hipStream_t stream) {
    const float* logits = (const float*)d_in[0];
    const float* boxes  = (const float*)d_in[1];
    const float* masks  = (const float*)d_in[2];
    const float* tmask  = (const float*)d_in[3];
    const float* tbox   = (const float*)d_in[4];
    const int*   tvalid = (const int*)d_in[5];
    const unsigned char* vpad = (const unsigned char*)d_in[6];
    float* out = (float*)d_out;
    float* ws  = (float*)d_ws;

    targets_kernel<<<NBF, NT, 0, stream>>>(tmask, vpad, ws);
    partial_kernel<<<NBF * NQ, NTP, 0, stream>>>(masks, ws, ws + WS_PART);
    int write_idx = (out_size >= 2 * NQ + 4) ? 1 : 0;
    final_kernel<<<2, NT, 0, stream>>>(logits, boxes, tbox, tvalid, ws, out, write_idx);
}

// Round 7
// 314.102 us; speedup vs baseline: 1.3051x; 1.0260x over previous
//
#include <hip/hip_runtime.h>
#include <math.h>

#define NF 8
#define NQ 300
#define HSZ 96
#define WSZ 96
#define HW 9216
#define DTOT 73728
#define NT 256
#define NTP 192
#define NBF 16

// ws float offsets
#define WS_TGTY 0        // [16][96] max over h
#define WS_TGTX 1536     // [16][96] max over w
#define WS_TSUM 3072     // [16]
#define WS_YSUM 3088     // [16]
#define WS_XSUM 3104     // [16]
#define WS_TBT  3200     // u64[16][192] transposed tmask bits (6144 floats)
#define WS_PBT  9344     // u64[2][192] transposed vpad bits (768 floats)
#define WS_PART 10240    // [4800][8] partials

typedef unsigned long long u64;

__device__ __forceinline__ float sigmoid_fast(float x) {
    float e = __expf(-fabsf(x));
    float inv = __builtin_amdgcn_rcpf(1.f + e);
    return x >= 0.f ? inv : e * inv;
}

// one block per (b,f): target projections/sums + bit-pack tmask/vpad into
// per-partial-thread transposed u64s (thread t's nibble for iter k at bit 4k).
__global__ __launch_bounds__(NT)
void targets_kernel(const float* __restrict__ tm, const unsigned char* __restrict__ vpad,
                    float* __restrict__ ws) {
    int bf = blockIdx.x, t = threadIdx.x;
    int lane = t & 63, wv = t >> 6;
    __shared__ float tile[HSZ * 97];
    __shared__ unsigned bits_t[288];
    __shared__ unsigned bits_p[288];
    __shared__ float red[4][4];
    const float* base = tm + (size_t)bf * HW;
    float tsum = 0.f;
    #pragma unroll
    for (int it = 0; it < 36; ++it) {
        int e = it * NT + t;
        float v = base[e];
        tsum += v;
        u64 bt = __ballot(v != 0.f);
        if (lane == 0) ((u64*)bits_t)[it * 4 + wv] = bt;
        tile[e + e / 96] = v;        // stride-97 padded
    }
    if ((bf & 7) == 0) {             // pack vpad plane b (block-uniform branch)
        int b = bf >> 3;
        const unsigned char* pp = vpad + (size_t)b * HW;
        #pragma unroll
        for (int it = 0; it < 36; ++it) {
            int e = it * NT + t;
            u64 bt = __ballot(pp[e] != 0);
            if (lane == 0) ((u64*)bits_p)[it * 4 + wv] = bt;
        }
    }
    __syncthreads();

    // transpose bits: partial thread t (0..191) owns elements 4*(t+192k)+j
    // -> plane bit dword (t>>3)+24k, shift (t&7)*4. Assemble 12 nibbles.
    if (t < NTP) {
        int widx = t >> 3, sh = (t & 7) * 4;
        u64 v = 0;
        #pragma unroll
        for (int k = 0; k < 12; ++k) {
            unsigned nib = (bits_t[k * 24 + widx] >> sh) & 0xFu;
            v |= (u64)nib << (4 * k);
        }
        ((u64*)(ws + WS_TBT))[bf * NTP + t] = v;
        if ((bf & 7) == 0) {
            int b = bf >> 3;
            u64 p = 0;
            #pragma unroll
            for (int k = 0; k < 12; ++k) {
                unsigned nib = (bits_p[k * 24 + widx] >> sh) & 0xFu;
                p |= (u64)nib << (4 * k);
            }
            ((u64*)(ws + WS_PBT))[b * NTP + t] = p;
        }
    }

    float ysum = 0.f, xsum = 0.f;
    if (t < 96) {
        float m = -INFINITY;
        #pragma unroll 8
        for (int h = 0; h < HSZ; ++h) m = fmaxf(m, tile[h * 97 + t]);
        ws[WS_TGTY + bf * 96 + t] = m;
        ysum = m;
    } else if (t < 192) {
        int hh = t - 96;
        float m = -INFINITY;
        #pragma unroll 8
        for (int w = 0; w < WSZ; ++w) m = fmaxf(m, tile[hh * 97 + w]);
        ws[WS_TGTX + bf * 96 + hh] = m;
        xsum = m;
    }
    float v0 = tsum, v1 = ysum, v2 = xsum;
    #pragma unroll
    for (int off = 32; off > 0; off >>= 1) {
        v0 += __shfl_down(v0, off, 64);
        v1 += __shfl_down(v1, off, 64);
        v2 += __shfl_down(v2, off, 64);
    }
    if (lane == 0) { red[wv][0] = v0; red[wv][1] = v1; red[wv][2] = v2; }
    __syncthreads();
    if (t == 0) {
        #pragma unroll
        for (int w = 1; w < 4; ++w) { v0 += red[w][0]; v1 += red[w][1]; v2 += red[w][2]; }
        ws[WS_TSUM + bf] = v0;
        ws[WS_YSUM + bf] = v1;
        ws[WS_XSUM + bf] = v2;
    }
}

// one block per (b,f,q), 192 threads. Column-strip mapping: thread t owns
// cols 4*w4..4*w4+3 (w4=t%24) and rows g+8k (g=t/24, k=0..11). float4 index
// = t + 192k (coalesced). Bits come from ONE u64 per thread (transposed in
// targets_kernel). No explicit prefetch (R3/R5 spilled); unroll capped at 3.
__global__ __launch_bounds__(NTP, 8)
void partial_kernel(const float* __restrict__ masks, const float* __restrict__ ws,
                    float* __restrict__ part) {
    int blk = blockIdx.x;
    int bf = blk / NQ;
    int q  = blk - bf * NQ;
    int b  = bf >> 3;
    int t  = threadIdx.x;
    int w4 = t % 24;
    int g  = t / 24;

    __shared__ float rowp[HSZ * 25];     // row-max partials, 25-padded
    __shared__ float colp[8 * HSZ];      // col-max partials per g
    __shared__ float red[3][8];

    const float4* mrow = (const float4*)(masks + (size_t)(bf * NQ + q) * HW);
    const u64 tw64 = ((const u64*)(ws + WS_TBT))[bf * NTP + t];
    const u64 pw64 = ((const u64*)(ws + WS_PBT))[b * NTP + t];

    float focal = 0.f, dnum = 0.f, dden = 0.f;
    float cm0 = -INFINITY, cm1 = -INFINITY, cm2 = -INFINITY, cm3 = -INFINITY;

    #pragma unroll 3
    for (int k = 0; k < 12; ++k) {
        float4 cur = mrow[k * NTP + t];
        unsigned tn = (unsigned)(tw64 >> (4 * k)) & 0xFu;
        unsigned pn = (unsigned)(pw64 >> (4 * k)) & 0xFu;

        float xs[4] = {cur.x, cur.y, cur.z, cur.w};
        if (pn) {                                 // execz-skipped when no padding
            #pragma unroll
            for (int j = 0; j < 4; ++j)
                if ((pn >> j) & 1u) xs[j] = 0.f;
        }
        #pragma unroll
        for (int j = 0; j < 4; ++j) {
            float x = xs[j];
            bool bit = (tn >> j) & 1u;
            float ee = __expf(-fabsf(x));
            float se = 1.f + ee;
            float inv = __builtin_amdgcn_rcpf(se);
            bool pos = x >= 0.f;
            float s   = pos ? inv : ee * inv;      // sigmoid(x)
            float oms = pos ? ee * inv : inv;      // sigmoid(-x) = 1-s
            float L = __logf(se);                   // log1p(exp(-|x|))
            float rp = fmaxf(x, 0.f);
            float ce = (bit ? rp - x : rp) + L;     // softplus of the right sign
            float omp = bit ? oms : s;              // 1 - p_t
            float at = bit ? 0.25f : 0.75f;         // alpha_t
            focal = fmaf(at * ce, omp * omp, focal);
            dnum += bit ? s : 0.f;
            dden += s;
        }
        cm0 = fmaxf(cm0, xs[0]); cm1 = fmaxf(cm1, xs[1]);
        cm2 = fmaxf(cm2, xs[2]); cm3 = fmaxf(cm3, xs[3]);
        float rm = fmaxf(fmaxf(xs[0], xs[1]), fmaxf(xs[2], xs[3]));
        rowp[(g + 8 * k) * 25 + w4] = rm;
    }
    ((float4*)colp)[g * 24 + w4] = make_float4(cm0, cm1, cm2, cm3);
    __syncthreads();

    float pYn = 0.f, pYd = 0.f, pXn = 0.f, pXd = 0.f;
    if (t < 96) {
        float m = colp[t];
        #pragma unroll
        for (int gg = 1; gg < 8; ++gg) m = fmaxf(m, colp[gg * 96 + t]);
        float sg = sigmoid_fast(m);
        pYd = sg;
        pYn = sg * ws[WS_TGTY + bf * 96 + t];
    } else {
        int r = t - 96;
        float m = rowp[r * 25];
        #pragma unroll
        for (int w = 1; w < 24; ++w) m = fmaxf(m, rowp[r * 25 + w]);
        float sg = sigmoid_fast(m);
        pXd = sg;
        pXn = sg * ws[WS_TGTX + bf * 96 + r];
    }

    // single-barrier 7-way block reduction over 3 waves
    float v[7] = {focal, dnum, dden, pYn, pYd, pXn, pXd};
    #pragma unroll
    for (int k = 0; k < 7; ++k)
        #pragma unroll
        for (int off = 32; off > 0; off >>= 1) v[k] += __shfl_down(v[k], off, 64);
    int wv = t >> 6, lane = t & 63;
    if (lane == 0) {
        #pragma unroll
        for (int k = 0; k < 7; ++k) red[wv][k] = v[k];
    }
    __syncthreads();
    if (t == 0) {
        #pragma unroll
        for (int w = 1; w < 3; ++w)
            #pragma unroll
            for (int k = 0; k < 7; ++k) v[k] += red[w][k];
        float4* p = (float4*)(part + (size_t)blk * 8);
        p[0] = make_float4(v[0], v[1], v[2], v[3]);
        p[1] = make_float4(v[4], v[5], v[6], 0.f);
    }
}

// one thread per (b,q), grid 10x64: combine partials + class/bbox/giou
__global__ __launch_bounds__(64)
void combine_kernel(const float* __restrict__ logits, const float* __restrict__ boxes,
                    const float* __restrict__ tbox, const int* __restrict__ tvalid,
                    const float* __restrict__ ws, float* __restrict__ out) {
    int gid = blockIdx.x * 64 + threadIdx.x;
    if (gid >= 2 * NQ) return;
    int b = gid / NQ, q = gid - b * NQ;
    const float* part = ws + WS_PART;

    float focal = 0.f, dnum = 0.f, dden = 0.f;
    float pYn = 0.f, pYd = 0.f, pXn = 0.f, pXd = 0.f;
    float tsum = 0.f, ysum = 0.f, xsum = 0.f;
    #pragma unroll
    for (int f = 0; f < NF; ++f) {
        int bf = b * NF + f;
        const float4* p = (const float4*)(part + (size_t)(bf * NQ + q) * 8);
        float4 pa = p[0], pbv = p[1];
        focal += pa.x; dnum += pa.y; dden += pa.z; pYn += pa.w;
        pYd += pbv.x; pXn += pbv.y; pXd += pbv.z;
        tsum += ws[WS_TSUM + bf];
        ysum += ws[WS_YSUM + bf];
        xsum += ws[WS_XSUM + bf];
    }
    float cost_mask = focal / (float)DTOT;
    float cost_dice = -(2.f * dnum + 1.f) / (dden + tsum + 1.f);
    float coefY = (2.f * pYn + 1.f) / (pYd + ysum + 1.f);
    float coefX = (2.f * pXn + 1.f) / (pXd + xsum + 1.f);
    float cost_proj = -0.5f * (coefY + coefX);

    float wsum = 0.f, cls = 0.f, cb = 0.f, cg = 0.f;
    #pragma unroll
    for (int f = 0; f < NF; ++f) {
        float wv = (tvalid[b * NF + f] != 0) ? 1.f : 0.f;
        wsum += wv;
        float lg = logits[(b * NF + f) * NQ + q];
        float p = sigmoid_fast(lg);
        float negc = 0.75f * p * p * (-__logf(1.f - p + 1e-8f));
        float posc = 0.25f * (1.f - p) * (1.f - p) * (-__logf(p + 1e-8f));
        cls += (posc - negc) * wv;

        const float* bx = boxes + (size_t)((b * NF + f) * NQ + q) * 4;
        const float* tbp = tbox + (b * NF + f) * 4;
        float cx = bx[0], cy = bx[1], bw = bx[2], bh = bx[3];
        float tcx = tbp[0], tcy = tbp[1], tbw = tbp[2], tbh = tbp[3];
        cb += fabsf(cx - tcx) + fabsf(cy - tcy) + fabsf(bw - tbw) + fabsf(bh - tbh);
        float sx1 = cx - 0.5f * bw, sy1 = cy - 0.5f * bh;
        float sx2 = cx + 0.5f * bw, sy2 = cy + 0.5f * bh;
        float tx1 = tcx - 0.5f * tbw, ty1 = tcy - 0.5f * tbh;
        float tx2 = tcx + 0.5f * tbw, ty2 = tcy + 0.5f * tbh;
        float a1 = (sx2 - sx1) * (sy2 - sy1), a2 = (tx2 - tx1) * (ty2 - ty1);
        float iw = fmaxf(fminf(sx2, tx2) - fmaxf(sx1, tx1), 0.f);
        float ih = fmaxf(fminf(sy2, ty2) - fmaxf(sy1, ty1), 0.f);
        float inter = iw * ih;
        float uni = a1 + a2 - inter;
        float iou = inter / uni;
        float cw = fmaxf(fmaxf(sx2, tx2) - fminf(sx1, tx1), 0.f);
        float chh = fmaxf(fmaxf(sy2, ty2) - fminf(sy1, ty1), 0.f);
        float areac = cw * chh;
        cg += -(iou - (areac - uni) / areac);
    }
    cls /= wsum;
    out[b * NQ + q] = cls + 0.125f * cb + 0.125f * cg + cost_mask + cost_dice + cost_proj;
}

__global__ __launch_bounds__(NT)
void argmin_kernel(float* __restrict__ out, int write_idx) {
    int b = blockIdx.x, t = threadIdx.x;
    float best = INFINITY;
    int bi = 0x7fffffff;
    for (int q = t; q < NQ; q += NT) {
        float v = out[b * NQ + q];
        if (v < best) { best = v; bi = q; }
    }
    #pragma unroll
    for (int off = 32; off > 0; off >>= 1) {
        float ov = __shfl_down(best, off, 64);
        int oi = __shfl_down(bi, off, 64);
        if (ov < best || (ov == best && oi < bi)) { best = ov; bi = oi; }
    }
    __shared__ float rv[4];
    __shared__ int ri[4];
    int wv = t >> 6, lane = t & 63;
    if (lane == 0) { rv[wv] = best; ri[wv] = bi; }
    __syncthreads();
    if (t == 0 && write_idx) {
        #pragma unroll
        for (int w = 1; w < 4; ++w) {
            if (rv[w] < best || (rv[w] == best && ri[w] < bi)) { best = rv[w]; bi = ri[w]; }
        }
        out[2 * NQ + b] = (float)bi;       // src_ind
        out[2 * NQ + 2 + b] = 0.f;         // tgt_ind
    }
}

extern "C" void kernel_launch(void* const* d_in, const int* in_sizes, int n_in,
                              void* d_out, int out_size, void* d_ws, size_t ws_size,
                              hipStream_t stream) {
    const float* logits = (const float*)d_in[0];
    const float* boxes  = (const float*)d_in[1];
    const float* masks  = (const float*)d_in[2];
    const float* tmask  = (const float*)d_in[3];
    const float* tbox   = (const float*)d_in[4];
    const int*   tvalid = (const int*)d_in[5];
    const unsigned char* vpad = (const unsigned char*)d_in[6];
    float* out = (float*)d_out;
    float* ws  = (float*)d_ws;

    targets_kernel<<<NBF, NT, 0, stream>>>(tmask, vpad, ws);
    partial_kernel<<<NBF * NQ, NTP, 0, stream>>>(masks, ws, ws + WS_PART);
    combine_kernel<<<(2 * NQ + 63) / 64, 64, 0, stream>>>(logits, boxes, tbox, tvalid, ws, out);
    int write_idx = (out_size >= 2 * NQ + 4) ? 1 : 0;
    argmin_kernel<<<2, NT, 0, stream>>>(out, write_idx);
}